// Round 1
// baseline (835.345 us; speedup 1.0000x reference)
//
#include <hip/hip_runtime.h>
#include <stdint.h>

#define BB 8
#define LL 4096
#define DD 64

// d_ws layout: [0..3]: uint32 flag (1 = mask is 1-byte bool, 0 = int32),
// offset 256: float lsums[BB*LL] (row sums of exp).

__global__ void detect_mask_kernel(const uint32_t* __restrict__ w, uint32_t* __restrict__ flag) {
    __shared__ int nonbin;
    if (threadIdx.x == 0) nonbin = 0;
    __syncthreads();
    int bad = 0;
    for (int i = threadIdx.x; i < 4096; i += 256) bad |= (w[i] > 1u) ? 1 : 0;
    if (bad) atomicOr(&nonbin, 1);
    __syncthreads();
    if (threadIdx.x == 0) *flag = (uint32_t)(nonbin != 0);
}

// K1: attn_unnorm[b,q,k] = mask ? 0 : exp(q.k/8); lsums[b,q] = sum_k attn_unnorm
__global__ __launch_bounds__(256, 2) void qk_exp_kernel(
    const float* __restrict__ qg_, const float* __restrict__ kg_,
    const void* __restrict__ maskv, const uint32_t* __restrict__ flagp,
    float* __restrict__ attn, float* __restrict__ lsums)
{
    __shared__ float Qs[64][68];      // padded: broadcast reads, 2-way max
    __shared__ float Ks[128 * 64];    // XOR-swizzled 16B chunks
    const int tid = threadIdx.x;
    const int tx = tid & 15, ty = tid >> 4;
    const int q0 = blockIdx.x * 64;
    const int b  = blockIdx.y;
    const bool mbyte = (*flagp != 0);

    // stage Q tile (64x64 f32), coalesced
    {
        const float4* qg = (const float4*)(qg_ + ((size_t)(b * LL + q0)) * DD);
        #pragma unroll
        for (int it = 0; it < 4; ++it) {
            int idx = it * 256 + tid;
            int r = idx >> 4, c4 = idx & 15;
            *(float4*)&Qs[r][c4 * 4] = qg[idx];
        }
    }

    const float4*  kg  = (const float4*)(kg_ + (size_t)b * LL * DD);
    const uint8_t* m8  = (const uint8_t*)maskv;
    const int*     m32 = (const int*)maskv;
    float lsum[4] = {0.f, 0.f, 0.f, 0.f};

    for (int kt = 0; kt < LL / 128; ++kt) {
        __syncthreads();
        // stage K tile (128x64 f32) with chunk swizzle: chunk' = c4 ^ (r&7) ^ ((r>>3)&7)
        #pragma unroll
        for (int it = 0; it < 8; ++it) {
            int idx = it * 256 + tid;
            int r = idx >> 4, c4 = idx & 15;
            int swz = c4 ^ (r & 7) ^ ((r >> 3) & 7);
            *(float4*)&Ks[r * 64 + swz * 4] = kg[kt * 2048 + idx];
        }
        __syncthreads();

        float s[4][8];
        #pragma unroll
        for (int i = 0; i < 4; ++i)
            #pragma unroll
            for (int j = 0; j < 8; ++j) s[i][j] = 0.f;

        #pragma unroll 4
        for (int d4 = 0; d4 < 16; ++d4) {
            float4 qv[4];
            #pragma unroll
            for (int i = 0; i < 4; ++i)
                qv[i] = *(const float4*)&Qs[ty * 4 + i][d4 * 4];
            #pragma unroll
            for (int j = 0; j < 8; ++j) {
                int r = tx * 8 + j;
                int swz = d4 ^ (r & 7) ^ ((r >> 3) & 7);
                float4 kv = *(const float4*)&Ks[r * 64 + swz * 4];
                #pragma unroll
                for (int i = 0; i < 4; ++i)
                    s[i][j] += qv[i].x * kv.x + qv[i].y * kv.y + qv[i].z * kv.z + qv[i].w * kv.w;
            }
        }

        // mask + exp + store unnormalized P, accumulate row sums
        const int kb = kt * 128 + tx * 8;
        #pragma unroll
        for (int i = 0; i < 4; ++i) {
            const size_t moff = ((size_t)(b * LL + q0 + ty * 4 + i)) * LL + kb;
            unsigned mk[8];
            if (mbyte) {
                uint64_t mw = *(const uint64_t*)(m8 + moff);
                #pragma unroll
                for (int j = 0; j < 8; ++j) mk[j] = (unsigned)((mw >> (8 * j)) & 0xffu);
            } else {
                int4 a = *(const int4*)(m32 + moff);
                int4 c = *(const int4*)(m32 + moff + 4);
                mk[0] = a.x; mk[1] = a.y; mk[2] = a.z; mk[3] = a.w;
                mk[4] = c.x; mk[5] = c.y; mk[6] = c.z; mk[7] = c.w;
            }
            float p[8];
            float rs = 0.f;
            #pragma unroll
            for (int j = 0; j < 8; ++j) {
                float pv = mk[j] ? 0.f : __expf(s[i][j] * 0.125f);
                p[j] = pv;
                rs += pv;
            }
            lsum[i] += rs;
            *(float4*)(attn + moff)     = make_float4(p[0], p[1], p[2], p[3]);
            *(float4*)(attn + moff + 4) = make_float4(p[4], p[5], p[6], p[7]);
        }
    }

    // reduce lsum over the 16 tx lanes of each row group
    #pragma unroll
    for (int off = 1; off < 16; off <<= 1)
        #pragma unroll
        for (int i = 0; i < 4; ++i)
            lsum[i] += __shfl_xor(lsum[i], off, 64);
    if (tx == 0) {
        #pragma unroll
        for (int i = 0; i < 4; ++i)
            lsums[b * LL + q0 + ty * 4 + i] = lsum[i];
    }
}

// K2: attn /= l (in place) fused with out = attn @ V
__global__ __launch_bounds__(256, 2) void norm_pv_kernel(
    const float* __restrict__ vg_, const float* __restrict__ lsums,
    float* __restrict__ attn, float* __restrict__ outp)
{
    __shared__ float Ps[64][132];   // pad 132: 16B-aligned rows, 2-way max on reads
    __shared__ float Vs[128][68];
    __shared__ float rls[64];
    const int tid = threadIdx.x;
    const int tx = tid & 15, ty = tid >> 4;
    const int q0 = blockIdx.x * 64;
    const int b  = blockIdx.y;
    if (tid < 64) rls[tid] = 1.0f / lsums[b * LL + q0 + tid];

    float acc[4][4];
    #pragma unroll
    for (int i = 0; i < 4; ++i)
        #pragma unroll
        for (int j = 0; j < 4; ++j) acc[i][j] = 0.f;

    const float4* vg = (const float4*)(vg_ + (size_t)b * LL * DD);

    for (int kt = 0; kt < 32; ++kt) {
        __syncthreads();
        // stage V tile (128x64)
        #pragma unroll
        for (int it = 0; it < 8; ++it) {
            int idx = it * 256 + tid;
            int r = idx >> 4, c4 = idx & 15;
            *(float4*)&Vs[r][c4 * 4] = vg[kt * 2048 + idx];
        }
        // stage P tile (64x128): read unnormalized, scale, write back + to LDS
        #pragma unroll
        for (int it = 0; it < 8; ++it) {
            int idx = it * 256 + tid;
            int r = idx >> 5, c4 = idx & 31;
            size_t off = ((size_t)(b * LL + q0 + r)) * LL + kt * 128 + c4 * 4;
            float4 pv = *(const float4*)(attn + off);
            float rl = rls[r];
            pv.x *= rl; pv.y *= rl; pv.z *= rl; pv.w *= rl;
            *(float4*)(attn + off) = pv;
            *(float4*)&Ps[r][c4 * 4] = pv;
        }
        __syncthreads();

        #pragma unroll 4
        for (int k4 = 0; k4 < 32; ++k4) {
            float4 p4[4];
            #pragma unroll
            for (int i = 0; i < 4; ++i)
                p4[i] = *(const float4*)&Ps[ty * 4 + i][k4 * 4];
            float4 vv[4];
            #pragma unroll
            for (int m = 0; m < 4; ++m)
                vv[m] = *(const float4*)&Vs[k4 * 4 + m][tx * 4];
            #pragma unroll
            for (int i = 0; i < 4; ++i) {
                acc[i][0] += p4[i].x * vv[0].x + p4[i].y * vv[1].x + p4[i].z * vv[2].x + p4[i].w * vv[3].x;
                acc[i][1] += p4[i].x * vv[0].y + p4[i].y * vv[1].y + p4[i].z * vv[2].y + p4[i].w * vv[3].y;
                acc[i][2] += p4[i].x * vv[0].z + p4[i].y * vv[1].z + p4[i].z * vv[2].z + p4[i].w * vv[3].z;
                acc[i][3] += p4[i].x * vv[0].w + p4[i].y * vv[1].w + p4[i].z * vv[2].w + p4[i].w * vv[3].w;
            }
        }
    }

    #pragma unroll
    for (int i = 0; i < 4; ++i) {
        float4 o = make_float4(acc[i][0], acc[i][1], acc[i][2], acc[i][3]);
        *(float4*)(outp + ((size_t)(b * LL + q0 + ty * 4 + i)) * DD + tx * 4) = o;
    }
}

extern "C" void kernel_launch(void* const* d_in, const int* in_sizes, int n_in,
                              void* d_out, int out_size, void* d_ws, size_t ws_size,
                              hipStream_t stream) {
    const float* q = (const float*)d_in[0];
    const float* k = (const float*)d_in[1];
    const float* v = (const float*)d_in[2];
    const void* mask = d_in[3];
    float* attn = (float*)d_out;
    float* outp = attn + (size_t)BB * LL * LL;
    uint32_t* flagp = (uint32_t*)d_ws;
    float* lsums = (float*)((char*)d_ws + 256);

    detect_mask_kernel<<<1, 256, 0, stream>>>((const uint32_t*)mask, flagp);
    qk_exp_kernel<<<dim3(LL / 64, BB), 256, 0, stream>>>(q, k, mask, flagp, attn, lsums);
    norm_pv_kernel<<<dim3(LL / 64, BB), 256, 0, stream>>>(v, lsums, attn, outp);
}